// Round 4
// baseline (990.901 us; speedup 1.0000x reference)
//
#include <hip/hip_runtime.h>
#include <math.h>

#define HW 100
#define FIN 128
#define NC 8        // XCD classes

// ---------------- init ----------------
__global__ void k_init(int* __restrict__ intdeg, int* __restrict__ cursor,
                       float* __restrict__ accums, int n) {
    int i = blockIdx.x * blockDim.x + threadIdx.x;
    int st = gridDim.x * blockDim.x;
    for (; i < n; i += st) { intdeg[i] = 0; cursor[i] = 0; }
    if (blockIdx.x == 0 && threadIdx.x == 0) { accums[0] = 0.f; accums[1] = 0.f; }
}

// ---------------- degree count, XCD-partitioned by dst range ----------------
__global__ __launch_bounds__(256) void k_deg(const int* __restrict__ dst, int E,
                                             int* __restrict__ intdeg, int N) {
    int cls = blockIdx.x & (NC - 1);
    int part = N / NC;
    int lo = cls * part;
    int hi = (cls == NC - 1) ? N : lo + part;
    int nper = (gridDim.x / NC) * blockDim.x;
    int i = (blockIdx.x >> 3) * blockDim.x + threadIdx.x;
    for (; i < E; i += nper) {
        int d = dst[i];
        if (d >= lo && d < hi) atomicAdd(&intdeg[d], 1);
    }
}

// ---------------- dinv ----------------
__global__ void k_dinv(const int* __restrict__ intdeg, float* __restrict__ dinv, int n) {
    int i = blockIdx.x * blockDim.x + threadIdx.x;
    if (i < n) dinv[i] = rsqrtf((float)intdeg[i] + 1.0f);   // +1 self loop
}

// ---------------- 2-level exclusive scan of intdeg -> offsets ----------------
__global__ void k_scan1(const int* __restrict__ deg, int n, int* __restrict__ blockTotals) {
    __shared__ int s[256];
    int base = blockIdx.x * 1024 + threadIdx.x * 4;
    int tsum = 0;
    #pragma unroll
    for (int j = 0; j < 4; ++j) { int idx = base + j; tsum += (idx < n) ? deg[idx] : 0; }
    s[threadIdx.x] = tsum; __syncthreads();
    for (int off = 128; off; off >>= 1) {
        if (threadIdx.x < off) s[threadIdx.x] += s[threadIdx.x + off];
        __syncthreads();
    }
    if (threadIdx.x == 0) blockTotals[blockIdx.x] = s[0];
}

__global__ void k_scan2(const int* __restrict__ blockTotals, int nb,
                        int* __restrict__ blockOffsets, int* __restrict__ offsets, int n) {
    if (blockIdx.x == 0 && threadIdx.x == 0) {
        int run = 0;
        for (int i = 0; i < nb; ++i) { blockOffsets[i] = run; run += blockTotals[i]; }
        offsets[n] = run;
    }
}

__global__ void k_scan3(const int* __restrict__ deg, int n,
                        const int* __restrict__ blockOffsets, int* __restrict__ offsets) {
    __shared__ int s[256];
    int tid = threadIdx.x;
    int base = blockIdx.x * 1024 + tid * 4;
    int v[4]; int tsum = 0;
    #pragma unroll
    for (int j = 0; j < 4; ++j) { int idx = base + j; v[j] = (idx < n) ? deg[idx] : 0; tsum += v[j]; }
    s[tid] = tsum; __syncthreads();
    for (int off = 1; off < 256; off <<= 1) {
        int x = (tid >= off) ? s[tid - off] : 0;
        __syncthreads();
        s[tid] += x;
        __syncthreads();
    }
    int run = blockOffsets[blockIdx.x] + (s[tid] - tsum);
    #pragma unroll
    for (int j = 0; j < 4; ++j) { int idx = base + j; if (idx < n) offsets[idx] = run; run += v[j]; }
}

// ---------------- CSR fill (src only), XCD-partitioned by dst range ----------------
__global__ __launch_bounds__(256) void k_fill(const int* __restrict__ src,
                                              const int* __restrict__ dst, int E,
                                              const int* __restrict__ offsets,
                                              int* __restrict__ cursor,
                                              int* __restrict__ csr_src, int N) {
    int cls = blockIdx.x & (NC - 1);
    int part = N / NC;
    int lo = cls * part;
    int hi = (cls == NC - 1) ? N : lo + part;
    int nper = (gridDim.x / NC) * blockDim.x;
    int i = (blockIdx.x >> 3) * blockDim.x + threadIdx.x;
    for (; i < E; i += nper) {
        int d = dst[i];
        if (d >= lo && d < hi) {
            int pos = offsets[d] + atomicAdd(&cursor[d], 1);
            csr_src[pos] = src[i];
        }
    }
}

// ---------------- weight-chain collapse (verified) ----------------
__global__ void k_chain(const float* __restrict__ W1, const float* __restrict__ b1,
                        const float* __restrict__ Wh, const float* __restrict__ bh,
                        const float* __restrict__ fc1W, const float* __restrict__ fc1b,
                        const float* __restrict__ fc2W, const float* __restrict__ fc2b,
                        float* __restrict__ wstar, float* __restrict__ gammas) {
    __shared__ float v[HW], vn[HW];
    int t = threadIdx.x;
    if (t < HW) v[t] = fc2W[t];
    __syncthreads();
    if (t < HW) { float a = 0.f; for (int c = 0; c < HW; ++c) a += fc1W[t * HW + c] * v[c]; vn[t] = a; }
    __syncthreads();
    if (t < HW) v[t] = vn[t];
    __syncthreads();
    if (t == 0) {
        float a = 0.f; for (int c = 0; c < HW; ++c) a += bh[7 * HW + c] * v[c];
        float b = 0.f; for (int c = 0; c < HW; ++c) b += fc1b[c] * fc2W[c];
        gammas[9] = a + b + fc2b[0];
    }
    __syncthreads();
    for (int i = 7; i >= 0; --i) {
        const float* M = Wh + (size_t)i * HW * HW;
        if (t < HW) { float a = 0.f; for (int c = 0; c < HW; ++c) a += M[t * HW + c] * v[c]; vn[t] = a; }
        __syncthreads();
        if (t < HW) v[t] = vn[t];
        __syncthreads();
        if (t == 0) {
            const float* bb = (i >= 1) ? (bh + (size_t)(i - 1) * HW) : b1;
            float a = 0.f; for (int c = 0; c < HW; ++c) a += bb[c] * v[c];
            gammas[i + 1] = a;
        }
        __syncthreads();
    }
    { float a = 0.f; for (int c = 0; c < HW; ++c) a += W1[t * HW + c] * v[c]; wstar[t] = a; }
}

// ---------------- u0 = dinv * (x @ wstar)  (wave per row) ----------------
__global__ __launch_bounds__(256) void k_gemv(const float* __restrict__ x,
                                              const float* __restrict__ wstar,
                                              const float* __restrict__ dinv,
                                              float* __restrict__ u, int n) {
    __shared__ float ws[FIN];
    int tid = threadIdx.x;
    if (tid < FIN) ws[tid] = wstar[tid];
    __syncthreads();
    int node = blockIdx.x * 4 + (tid >> 6);
    int lane = tid & 63;
    if (node >= n) return;
    const float* xr = x + (size_t)node * FIN;
    float2 a = *reinterpret_cast<const float2*>(&xr[lane * 2]);
    float v = a.x * ws[lane * 2] + a.y * ws[lane * 2 + 1];
    #pragma unroll
    for (int off = 32; off; off >>= 1) v += __shfl_down(v, off);
    if (lane == 0) u[node] = v * dinv[node];
}

// ---------------- apply: u_new = dinv*(dinv*(sum u[src] + u) + gamma); y written on last ----
__global__ __launch_bounds__(256) void k_apply(const float* __restrict__ u,
                                               const int* __restrict__ csr_src,
                                               const int* __restrict__ offsets,
                                               const float* __restrict__ dinv,
                                               const float* __restrict__ gammas, int k,
                                               float* __restrict__ unew,
                                               float* __restrict__ ybuf, int n) {
    int i = blockIdx.x * blockDim.x + threadIdx.x;
    if (i >= n) return;
    int beg = offsets[i], end = offsets[i + 1];
    float a0 = u[i], a1 = 0.f, a2 = 0.f, a3 = 0.f;
    int e = beg;
    for (; e + 4 <= end; e += 4) {
        a0 += u[csr_src[e]];
        a1 += u[csr_src[e + 1]];
        a2 += u[csr_src[e + 2]];
        a3 += u[csr_src[e + 3]];
    }
    for (; e < end; ++e) a0 += u[csr_src[e]];
    float acc = (a0 + a1) + (a2 + a3);
    float di = dinv[i];
    float y = di * acc + gammas[k];
    unew[i] = di * y;
    if (ybuf) ybuf[i] = y;
}

// ---------------- pos = sum(labels) ----------------
__global__ void k_pos(const float* __restrict__ labels, int n, float* __restrict__ accums) {
    __shared__ float s[256];
    float v = 0.f;
    for (int i = blockIdx.x * blockDim.x + threadIdx.x; i < n; i += gridDim.x * blockDim.x)
        v += labels[i];
    s[threadIdx.x] = v; __syncthreads();
    for (int off = 128; off; off >>= 1) {
        if (threadIdx.x < off) s[threadIdx.x] += s[threadIdx.x + off];
        __syncthreads();
    }
    if (threadIdx.x == 0) atomicAdd(&accums[0], s[0]);
}

// ---------------- sigmoid + weighted BCE ----------------
__global__ __launch_bounds__(256) void k_loss(const float* __restrict__ L,
                                              const float* __restrict__ labels,
                                              const float* __restrict__ accums,
                                              float* __restrict__ out_p,
                                              float* __restrict__ loss_accum, int n) {
    __shared__ float s[256];
    float pos = accums[0];
    float wpos = ((float)n - pos) / pos;
    float acc = 0.f;
    for (int i = blockIdx.x * blockDim.x + threadIdx.x; i < n; i += gridDim.x * blockDim.x) {
        float logit = L[i];
        float p = 1.f / (1.f + expf(-logit));
        out_p[i] = p;
        float pc = fminf(fmaxf(p, 1e-7f), 1.f - 1e-7f);
        float l = labels[i];
        float w = wpos * l + 1.f;
        acc += w * (-(l * logf(pc) + (1.f - l) * logf(1.f - pc)));
    }
    s[threadIdx.x] = acc; __syncthreads();
    for (int off = 128; off; off >>= 1) {
        if (threadIdx.x < off) s[threadIdx.x] += s[threadIdx.x + off];
        __syncthreads();
    }
    if (threadIdx.x == 0) atomicAdd(loss_accum, s[0]);
}

__global__ void k_final(const float* __restrict__ accums, float* __restrict__ out0, int n) {
    if (blockIdx.x == 0 && threadIdx.x == 0) out0[0] = accums[1] / (float)n;
}

// ---------------- launch ----------------
extern "C" void kernel_launch(void* const* d_in, const int* in_sizes, int n_in,
                              void* d_out, int out_size, void* d_ws, size_t ws_size,
                              hipStream_t stream) {
    const float* x      = (const float*)d_in[0];
    const int*   edge   = (const int*)d_in[1];
    const float* labels = (const float*)d_in[2];
    const float* W1     = (const float*)d_in[3];
    const float* b1     = (const float*)d_in[4];
    const float* Wh     = (const float*)d_in[5];
    const float* bh     = (const float*)d_in[6];
    const float* fc1W   = (const float*)d_in[7];
    const float* fc1b   = (const float*)d_in[8];
    const float* fc2W   = (const float*)d_in[9];
    const float* fc2b   = (const float*)d_in[10];

    const int N = in_sizes[0] / FIN;   // 100000
    const int E = in_sizes[1] / 2;     // 1600000
    const int* srcIdx = edge;
    const int* dstIdx = edge + E;

    size_t o = 0;
    auto carve = [&](size_t bytes) {
        void* p = (char*)d_ws + o;
        o += (bytes + 511) & ~(size_t)511;
        return p;
    };
    float* dinv        = (float*)carve((size_t)N * 4);
    int*   offsets     = (int*)  carve((size_t)(N + 1) * 4);
    int*   intdeg      = (int*)  carve((size_t)N * 4);
    int*   cursor      = (int*)  carve((size_t)N * 4);
    int*   blockTotals = (int*)  carve(256 * 4);
    int*   blockOffs   = (int*)  carve(256 * 4);
    float* accums      = (float*)carve(2 * 4);
    float* wstar       = (float*)carve(FIN * 4);
    float* gammas      = (float*)carve(16 * 4);
    int*   csr_src     = (int*)  carve((size_t)E * 4);
    float* ua          = (float*)carve((size_t)N * 4);
    float* ub          = (float*)carve((size_t)N * 4);
    float* ybuf        = (float*)carve((size_t)N * 4);
    (void)ws_size; (void)n_in; (void)out_size;

    int NB = (N + 1023) / 1024;
    const int PART_BLOCKS = 1024;   // 128 blocks per XCD class

    k_init<<<256, 256, 0, stream>>>(intdeg, cursor, accums, N);
    k_deg<<<PART_BLOCKS, 256, 0, stream>>>(dstIdx, E, intdeg, N);
    k_dinv<<<(N + 255) / 256, 256, 0, stream>>>(intdeg, dinv, N);
    k_scan1<<<NB, 256, 0, stream>>>(intdeg, N, blockTotals);
    k_scan2<<<1, 64, 0, stream>>>(blockTotals, NB, blockOffs, offsets, N);
    k_scan3<<<NB, 256, 0, stream>>>(intdeg, N, blockOffs, offsets);
    k_fill<<<PART_BLOCKS, 256, 0, stream>>>(srcIdx, dstIdx, E, offsets, cursor, csr_src, N);
    k_pos<<<256, 256, 0, stream>>>(labels, N, accums);
    k_chain<<<1, FIN, 0, stream>>>(W1, b1, Wh, bh, fc1W, fc1b, fc2W, fc2b, wstar, gammas);

    k_gemv<<<(N + 3) / 4, 256, 0, stream>>>(x, wstar, dinv, ua, N);

    float* uo = ua; float* un = ub;
    for (int k = 1; k <= 9; ++k) {
        k_apply<<<(N + 255) / 256, 256, 0, stream>>>(uo, csr_src, offsets, dinv, gammas, k,
                                                     un, (k == 9) ? ybuf : nullptr, N);
        float* t = uo; uo = un; un = t;
    }

    float* outF = (float*)d_out;
    k_loss<<<512, 256, 0, stream>>>(ybuf, labels, accums, outF + 1, accums + 1, N);
    k_final<<<1, 64, 0, stream>>>(accums, outF, N);
}

// Round 5
// 671.549 us; speedup vs baseline: 1.4755x; 1.4755x over previous
//
#include <hip/hip_runtime.h>
#include <hip/hip_cooperative_groups.h>
#include <math.h>

namespace cg = cooperative_groups;

#define HW 100
#define FIN 128
#define NC 8
#define NBLK 256
#define TPB 256

// ---------------- init ----------------
__global__ void k_init(int* __restrict__ intdeg, int* __restrict__ cursor,
                       float* __restrict__ accums, int n) {
    int i = blockIdx.x * blockDim.x + threadIdx.x;
    int st = gridDim.x * blockDim.x;
    for (; i < n; i += st) { intdeg[i] = 0; cursor[i] = 0; }
    if (blockIdx.x == 0 && threadIdx.x == 0) { accums[0] = 0.f; accums[1] = 0.f; }
}

// ---------------- degree count, XCD-partitioned by dst range ----------------
__global__ __launch_bounds__(256) void k_deg(const int* __restrict__ dst, int E,
                                             int* __restrict__ intdeg, int N) {
    int cls = blockIdx.x & (NC - 1);
    int part = N / NC;
    int lo = cls * part;
    int hi = (cls == NC - 1) ? N : lo + part;
    int nper = (gridDim.x / NC) * blockDim.x;
    int i = (blockIdx.x >> 3) * blockDim.x + threadIdx.x;
    for (; i < E; i += nper) {
        int d = dst[i];
        if (d >= lo && d < hi) atomicAdd(&intdeg[d], 1);
    }
}

// ---------------- dinv ----------------
__global__ void k_dinv(const int* __restrict__ intdeg, float* __restrict__ dinv, int n) {
    int i = blockIdx.x * blockDim.x + threadIdx.x;
    if (i < n) dinv[i] = rsqrtf((float)intdeg[i] + 1.0f);   // +1 self loop
}

// ---------------- 2-level exclusive scan of intdeg -> offsets ----------------
__global__ void k_scan1(const int* __restrict__ deg, int n, int* __restrict__ blockTotals) {
    __shared__ int s[256];
    int base = blockIdx.x * 1024 + threadIdx.x * 4;
    int tsum = 0;
    #pragma unroll
    for (int j = 0; j < 4; ++j) { int idx = base + j; tsum += (idx < n) ? deg[idx] : 0; }
    s[threadIdx.x] = tsum; __syncthreads();
    for (int off = 128; off; off >>= 1) {
        if (threadIdx.x < off) s[threadIdx.x] += s[threadIdx.x + off];
        __syncthreads();
    }
    if (threadIdx.x == 0) blockTotals[blockIdx.x] = s[0];
}

__global__ void k_scan2(const int* __restrict__ blockTotals, int nb,
                        int* __restrict__ blockOffsets, int* __restrict__ offsets, int n) {
    if (blockIdx.x == 0 && threadIdx.x == 0) {
        int run = 0;
        for (int i = 0; i < nb; ++i) { blockOffsets[i] = run; run += blockTotals[i]; }
        offsets[n] = run;
    }
}

__global__ void k_scan3(const int* __restrict__ deg, int n,
                        const int* __restrict__ blockOffsets, int* __restrict__ offsets) {
    __shared__ int s[256];
    int tid = threadIdx.x;
    int base = blockIdx.x * 1024 + tid * 4;
    int v[4]; int tsum = 0;
    #pragma unroll
    for (int j = 0; j < 4; ++j) { int idx = base + j; v[j] = (idx < n) ? deg[idx] : 0; tsum += v[j]; }
    s[tid] = tsum; __syncthreads();
    for (int off = 1; off < 256; off <<= 1) {
        int x = (tid >= off) ? s[tid - off] : 0;
        __syncthreads();
        s[tid] += x;
        __syncthreads();
    }
    int run = blockOffsets[blockIdx.x] + (s[tid] - tsum);
    #pragma unroll
    for (int j = 0; j < 4; ++j) { int idx = base + j; if (idx < n) offsets[idx] = run; run += v[j]; }
}

// ---------------- CSR fill (src only), XCD-partitioned by dst range ----------------
__global__ __launch_bounds__(256) void k_fill(const int* __restrict__ src,
                                              const int* __restrict__ dst, int E,
                                              const int* __restrict__ offsets,
                                              int* __restrict__ cursor,
                                              int* __restrict__ csr_src, int N) {
    int cls = blockIdx.x & (NC - 1);
    int part = N / NC;
    int lo = cls * part;
    int hi = (cls == NC - 1) ? N : lo + part;
    int nper = (gridDim.x / NC) * blockDim.x;
    int i = (blockIdx.x >> 3) * blockDim.x + threadIdx.x;
    for (; i < E; i += nper) {
        int d = dst[i];
        if (d >= lo && d < hi) {
            int pos = offsets[d] + atomicAdd(&cursor[d], 1);
            csr_src[pos] = src[i];
        }
    }
}

// ---------------- the fused cooperative kernel ----------------
__global__ __launch_bounds__(TPB) void k_main(const float* __restrict__ x,
        const float* __restrict__ labels,
        const float* __restrict__ W1, const float* __restrict__ b1,
        const float* __restrict__ Wh, const float* __restrict__ bh,
        const float* __restrict__ fc1W, const float* __restrict__ fc1b,
        const float* __restrict__ fc2W, const float* __restrict__ fc2b,
        const int* __restrict__ csr_src, const int* __restrict__ offsets,
        const float* __restrict__ dinv,
        float* __restrict__ ua, float* __restrict__ ub, float* __restrict__ ybuf,
        float* __restrict__ accums, float* __restrict__ outF, int N) {
    cg::grid_group grid = cg::this_grid();
    __shared__ float v[HW], vn[HW], ws[FIN], gam[16];
    __shared__ float red[TPB];
    int tid = threadIdx.x;
    int chunk = (N + NBLK - 1) / NBLK;
    int nlo = blockIdx.x * chunk;
    if (nlo > N) nlo = N;
    int nhi = nlo + chunk; if (nhi > N) nhi = N;

    // ---- phase 0: weight-chain collapse, redundant per block (no inter-block dep) ----
    if (tid < HW) v[tid] = fc2W[tid];
    __syncthreads();
    float a;
    if (tid < HW) { a = 0.f; for (int c = 0; c < HW; ++c) a += fc1W[tid * HW + c] * v[c]; vn[tid] = a; }
    __syncthreads();
    if (tid < HW) v[tid] = vn[tid];
    __syncthreads();
    float p = (tid < HW) ? (bh[7 * HW + tid] * v[tid] + fc1b[tid] * fc2W[tid]) : 0.f;
    red[tid] = p; __syncthreads();
    for (int off = 128; off; off >>= 1) { if (tid < off) red[tid] += red[tid + off]; __syncthreads(); }
    if (tid == 0) gam[9] = red[0] + fc2b[0];
    __syncthreads();
    for (int i = 7; i >= 0; --i) {
        const float* M = Wh + (size_t)i * HW * HW;
        if (tid < HW) { a = 0.f; for (int c = 0; c < HW; ++c) a += M[tid * HW + c] * v[c]; vn[tid] = a; }
        __syncthreads();
        if (tid < HW) v[tid] = vn[tid];
        __syncthreads();
        const float* bb = (i >= 1) ? (bh + (size_t)(i - 1) * HW) : b1;
        p = (tid < HW) ? bb[tid] * v[tid] : 0.f;
        red[tid] = p; __syncthreads();
        for (int off = 128; off; off >>= 1) { if (tid < off) red[tid] += red[tid + off]; __syncthreads(); }
        if (tid == 0) gam[i + 1] = red[0];
        __syncthreads();
    }
    if (tid < FIN) { a = 0.f; for (int c = 0; c < HW; ++c) a += W1[tid * HW + c] * v[c]; ws[tid] = a; }
    __syncthreads();

    // ---- phase 1: gemv over chunk (wave per node, coalesced float2) + pos partial ----
    {
        int wid = tid >> 6, lane = tid & 63;
        for (int nb = nlo + wid; nb < nhi; nb += 4) {
            const float* xr = x + (size_t)nb * FIN;
            float2 xv = *reinterpret_cast<const float2*>(&xr[lane * 2]);
            float d = xv.x * ws[lane * 2] + xv.y * ws[lane * 2 + 1];
            #pragma unroll
            for (int off = 32; off; off >>= 1) d += __shfl_down(d, off);
            if (lane == 0) ua[nb] = d * dinv[nb];
        }
    }
    {
        float s = 0.f;
        for (int n = nlo + tid; n < nhi; n += TPB) s += labels[n];
        red[tid] = s; __syncthreads();
        for (int off = 128; off; off >>= 1) { if (tid < off) red[tid] += red[tid + off]; __syncthreads(); }
        if (tid == 0) atomicAdd(&accums[0], red[0]);
    }
    grid.sync();

    // ---- phase 2: 9 sparse applies, grid.sync between (csr slice stays L2-warm) ----
    const float* uo = ua; float* un = ub;
    for (int k = 1; k <= 9; ++k) {
        float gk = gam[k];
        for (int n = nlo + tid; n < nhi; n += TPB) {
            int beg = offsets[n], end = offsets[n + 1];
            float a0 = uo[n], a1 = 0.f, a2 = 0.f, a3 = 0.f;
            int e = beg;
            for (; e + 4 <= end; e += 4) {
                a0 += uo[csr_src[e]];
                a1 += uo[csr_src[e + 1]];
                a2 += uo[csr_src[e + 2]];
                a3 += uo[csr_src[e + 3]];
            }
            for (; e < end; ++e) a0 += uo[csr_src[e]];
            float di = dinv[n];
            float y = di * ((a0 + a1) + (a2 + a3)) + gk;
            un[n] = di * y;
            if (k == 9) ybuf[n] = y;
        }
        grid.sync();
        const float* t = uo; uo = un; un = (float*)t;
    }

    // ---- phase 3: sigmoid + weighted BCE ----
    {
        float pos = accums[0];
        float wpos = ((float)N - pos) / pos;
        float acc = 0.f;
        for (int n = nlo + tid; n < nhi; n += TPB) {
            float logit = ybuf[n];
            float pp = 1.f / (1.f + expf(-logit));
            outF[1 + n] = pp;
            float pc = fminf(fmaxf(pp, 1e-7f), 1.f - 1e-7f);
            float l = labels[n];
            float w = wpos * l + 1.f;
            acc += w * (-(l * logf(pc) + (1.f - l) * logf(1.f - pc)));
        }
        red[tid] = acc; __syncthreads();
        for (int off = 128; off; off >>= 1) { if (tid < off) red[tid] += red[tid + off]; __syncthreads(); }
        if (tid == 0) atomicAdd(&accums[1], red[0]);
    }
    grid.sync();
    if (blockIdx.x == 0 && tid == 0) outF[0] = accums[1] / (float)N;
}

// ---------------- launch ----------------
extern "C" void kernel_launch(void* const* d_in, const int* in_sizes, int n_in,
                              void* d_out, int out_size, void* d_ws, size_t ws_size,
                              hipStream_t stream) {
    const float* x      = (const float*)d_in[0];
    const int*   edge   = (const int*)d_in[1];
    const float* labels = (const float*)d_in[2];
    const float* W1     = (const float*)d_in[3];
    const float* b1     = (const float*)d_in[4];
    const float* Wh     = (const float*)d_in[5];
    const float* bh     = (const float*)d_in[6];
    const float* fc1W   = (const float*)d_in[7];
    const float* fc1b   = (const float*)d_in[8];
    const float* fc2W   = (const float*)d_in[9];
    const float* fc2b   = (const float*)d_in[10];

    const int N = in_sizes[0] / FIN;   // 100000
    const int E = in_sizes[1] / 2;     // 1600000
    const int* srcIdx = edge;
    const int* dstIdx = edge + E;

    size_t o = 0;
    auto carve = [&](size_t bytes) {
        void* p = (char*)d_ws + o;
        o += (bytes + 511) & ~(size_t)511;
        return p;
    };
    float* dinv        = (float*)carve((size_t)N * 4);
    int*   offsets     = (int*)  carve((size_t)(N + 1) * 4);
    int*   intdeg      = (int*)  carve((size_t)N * 4);
    int*   cursor      = (int*)  carve((size_t)N * 4);
    int*   blockTotals = (int*)  carve(256 * 4);
    int*   blockOffs   = (int*)  carve(256 * 4);
    float* accums      = (float*)carve(2 * 4);
    int*   csr_src     = (int*)  carve((size_t)E * 4);
    float* ua          = (float*)carve((size_t)N * 4);
    float* ub          = (float*)carve((size_t)N * 4);
    float* ybuf        = (float*)carve((size_t)N * 4);
    (void)ws_size; (void)n_in; (void)out_size;

    int NB = (N + 1023) / 1024;
    const int PART_BLOCKS = 1024;

    k_init<<<256, 256, 0, stream>>>(intdeg, cursor, accums, N);
    k_deg<<<PART_BLOCKS, 256, 0, stream>>>(dstIdx, E, intdeg, N);
    k_dinv<<<(N + 255) / 256, 256, 0, stream>>>(intdeg, dinv, N);
    k_scan1<<<NB, 256, 0, stream>>>(intdeg, N, blockTotals);
    k_scan2<<<1, 64, 0, stream>>>(blockTotals, NB, blockOffs, offsets, N);
    k_scan3<<<NB, 256, 0, stream>>>(intdeg, N, blockOffs, offsets);
    k_fill<<<PART_BLOCKS, 256, 0, stream>>>(srcIdx, dstIdx, E, offsets, cursor, csr_src, N);

    float* outF = (float*)d_out;
    int Nv = N;
    void* args[] = {(void*)&x, (void*)&labels, (void*)&W1, (void*)&b1, (void*)&Wh, (void*)&bh,
                    (void*)&fc1W, (void*)&fc1b, (void*)&fc2W, (void*)&fc2b,
                    (void*)&csr_src, (void*)&offsets, (void*)&dinv,
                    (void*)&ua, (void*)&ub, (void*)&ybuf,
                    (void*)&accums, (void*)&outF, (void*)&Nv};
    hipLaunchCooperativeKernel((const void*)k_main, dim3(NBLK), dim3(TPB), args, 0, stream);
}